// Round 3
// baseline (277.410 us; speedup 1.0000x reference)
//
#include <hip/hip_runtime.h>
#include <math.h>
#include <stdint.h>

typedef short bf16x8 __attribute__((ext_vector_type(8)));
typedef float f32x16 __attribute__((ext_vector_type(16)));
typedef unsigned short ushort_t;

// ---------------- old-path workspace layout (float offsets) ----------------
#define WS_POOLED 0
#define WS_CIN    2048
#define WS_COUT   4096
#define WS_SP9    6144
#define WS_K4     6432
#define WS_WF     8192

// ---------------- new-path workspace layout ----------------
// floats: part[32][32][64] at 0 (256 KB), cin 65536, cout 67584, sp9 69632, k4 69920
// bytes:  wfb at 512 KiB (2.36 MB), xb at 3 MiB (64 MiB)
#define NP_CIN  65536
#define NP_COUT 67584
#define NP_SP9  69632
#define NP_K4   69920
#define NP_WFB_BYTES (512 * 1024)
#define NP_XB_BYTES  (3 * 1024 * 1024)
#define NP_NEED ((size_t)(3 * 1024 * 1024) + (size_t)(64 * 1024 * 1024))

static __device__ __forceinline__ unsigned f2bf(float f) {
  unsigned u = __builtin_bit_cast(unsigned, f);
  return (u + 0x7FFFu + ((u >> 16) & 1u)) >> 16;   // RNE
}

// ---------------- convert+pool: x fp32 NCHW -> xb bf16 NHWC, pool partials ----------------
// grid: 32 b x 32 groups of 512 pixels; 256 threads; thread handles pixels p0+2t, p0+2t+1.
__global__ __launch_bounds__(256) void convert_kernel(const float* __restrict__ x,
                                                      ushort_t* __restrict__ xb,
                                                      float* __restrict__ part) {
  const int b = blockIdx.x >> 5;
  const int g = blockIdx.x & 31;
  const int p0 = g << 9;
  const int t = threadIdx.x;
  const int w = t >> 6;
  const int lane = t & 63;
  __shared__ float s_part[4 * 64];

  const int pa = p0 + 2 * t;
  ushort_t* outp = xb + (size_t)(b * 16384 + pa) * 64;

#pragma unroll 1
  for (int g8 = 0; g8 < 8; ++g8) {
    uint4 ca, cb;
    unsigned* cap = (unsigned*)&ca;
    unsigned* cbp = (unsigned*)&cb;
#pragma unroll
    for (int j = 0; j < 8; ++j) {
      const int ci = g8 * 8 + j;
      float2 v = *(const float2*)(x + ((size_t)(b * 64 + ci) * 16384) + pa);
      float psum = v.x + v.y;
#pragma unroll
      for (int off = 32; off > 0; off >>= 1) psum += __shfl_down(psum, off, 64);
      if (lane == 0) s_part[w * 64 + ci] = psum;
      unsigned ba = f2bf(v.x), bb = f2bf(v.y);
      if (j & 1) { cap[j >> 1] |= ba << 16; cbp[j >> 1] |= bb << 16; }
      else       { cap[j >> 1]  = ba;       cbp[j >> 1]  = bb; }
    }
    *(uint4*)(outp + g8 * 8)      = ca;
    *(uint4*)(outp + 64 + g8 * 8) = cb;
  }
  __syncthreads();
  if (t < 64)
    part[((size_t)b * 32 + g) * 64 + t] =
        s_part[t] + s_part[64 + t] + s_part[128 + t] + s_part[192 + t];
}

// ---------------- 1) global average pool (old path) ----------------
__global__ __launch_bounds__(256) void pool_kernel(const float* __restrict__ x,
                                                   float* __restrict__ pooled) {
  const int bc = blockIdx.x;
  const int tid = threadIdx.x;
  const float4* p = (const float4*)(x + (size_t)bc * 16384);
  float s = 0.f;
  for (int j = tid; j < 4096; j += 256) {
    float4 v = p[j];
    s += (v.x + v.y) + (v.z + v.w);
  }
#pragma unroll
  for (int off = 32; off > 0; off >>= 1) s += __shfl_down(s, off, 64);
  __shared__ float red[4];
  if ((tid & 63) == 0) red[tid >> 6] = s;
  __syncthreads();
  if (tid == 0) pooled[bc] = (red[0] + red[1] + red[2] + red[3]) * (1.f / 16384.f);
}

// ---------------- 2) attention chain, one block per batch ----------------
// pin: if n_part>0, per-group pool partial sums [32 b][n_part][64] (raw sums);
// else pooled [b][64] (already averaged).
__global__ __launch_bounds__(128) void att_kernel(
    const float* __restrict__ pin, int n_part,
    const float* __restrict__ fc_w, const float* __restrict__ ch_w, const float* __restrict__ ch_b,
    const float* __restrict__ f_w,  const float* __restrict__ f_b,
    const float* __restrict__ sp_w, const float* __restrict__ sp_b,
    const float* __restrict__ k_w,  const float* __restrict__ k_b,
    const float* __restrict__ fus_w1, const float* __restrict__ fus_b1,
    const float* __restrict__ fus_w2, const float* __restrict__ fus_b2,
    float* __restrict__ o_cin, float* __restrict__ o_cout,
    float* __restrict__ o_sp9, float* __restrict__ o_k4) {
  const int b = blockIdx.x;
  const int t = threadIdx.x;
  __shared__ float s_pool[64], s_a[16], s_att[128], s_sp[9], s_k[4], s_h[8],
      s_att2[128], s_red[2], s_w12[2];

  if (t < 64) {
    if (n_part > 0) {
      float s = 0.f;
      for (int g = 0; g < n_part; ++g) s += pin[((size_t)b * n_part + g) * 64 + t];
      s_pool[t] = s * (1.f / 16384.f);
    } else {
      s_pool[t] = pin[b * 64 + t];
    }
  }
  __syncthreads();

  if (t < 16) {
    float s = 0.f;
    for (int c = 0; c < 64; ++c) s += s_pool[c] * fc_w[t * 64 + c];
    s_a[t] = fmaxf(s, 0.f);
  }
  __syncthreads();

  if (t < 64) {
    float s = ch_b[t];
    for (int j = 0; j < 16; ++j) s += s_a[j] * ch_w[t * 16 + j];
    s_att[t] = 1.f / (1.f + expf(-s));
  } else {
    const int o = t - 64;
    float s = f_b[o];
    for (int j = 0; j < 16; ++j) s += s_a[j] * f_w[o * 16 + j];
    s_att[t] = 1.f / (1.f + expf(-s));
  }
  if (t < 9) {
    float s = sp_b[t];
    for (int j = 0; j < 16; ++j) s += s_a[j] * sp_w[t * 16 + j];
    s_sp[t] = 1.f / (1.f + expf(-s));
  }
  if (t < 4) {
    float s = k_b[t];
    for (int j = 0; j < 16; ++j) s += s_a[j] * k_w[t * 16 + j];
    s_k[t] = s;
  }
  __syncthreads();

  if (t < 8) {
    float s = fus_b1[t];
    for (int c = 0; c < 128; ++c) s += s_att[c] * fus_w1[t * 128 + c];
    s_h[t] = fmaxf(s, 0.f);
  }
  if (t == 127) {
    float m = fmaxf(fmaxf(s_k[0], s_k[1]), fmaxf(s_k[2], s_k[3]));
    float e0 = expf(s_k[0] - m), e1 = expf(s_k[1] - m);
    float e2 = expf(s_k[2] - m), e3 = expf(s_k[3] - m);
    float inv = 1.f / (e0 + e1 + e2 + e3);
    s_k[0] = e0 * inv; s_k[1] = e1 * inv; s_k[2] = e2 * inv; s_k[3] = e3 * inv;
  }
  __syncthreads();

  {
    float s = fus_b2[t];
    for (int j = 0; j < 8; ++j) s += s_h[j] * fus_w2[t * 8 + j];
    s_att2[t] = 1.f / (1.f + expf(-s));
  }
  __syncthreads();

  if (t < 2) {
    float s = 0.f;
    for (int c = 0; c < 64; ++c) s += s_att2[t * 64 + c];
    s_red[t] = s;
  }
  __syncthreads();
  if (t == 0) {
    float m = fmaxf(s_red[0], s_red[1]);
    float e1 = expf(s_red[0] - m), e2 = expf(s_red[1] - m);
    float inv = 1.f / (e1 + e2);
    s_w12[0] = e1 * inv;
    s_w12[1] = e2 * inv;
  }
  __syncthreads();

  if (t < 64) {
    o_cin[b * 64 + t]  = s_w12[0] * s_att[t];
    o_cout[b * 64 + t] = s_w12[1] * s_att[64 + t];
  }
  if (t < 9) o_sp9[b * 9 + t] = s_sp[t];
  if (t < 4) o_k4[b * 4 + t] = s_k[t];
}

// ---------------- 3) fused per-sample weight -> bf16 [b][pq][o][i] ----------------
__global__ __launch_bounds__(256) void wf_kernel(const float* __restrict__ weight,
                                                 const float* __restrict__ cin,
                                                 const float* __restrict__ cout_,
                                                 const float* __restrict__ sp9,
                                                 const float* __restrict__ k4,
                                                 ushort_t* __restrict__ wfb) {
  const int bo = blockIdx.x;              // b*64 + o
  const int b = bo >> 6, o = bo & 63;
  const float co = cout_[b * 64 + o];
  const float k0 = k4[b * 4 + 0], k1 = k4[b * 4 + 1];
  const float k2 = k4[b * 4 + 2], k3 = k4[b * 4 + 3];
  for (int idx = threadIdx.x; idx < 576; idx += 256) {
    const int pq = idx >> 6, i = idx & 63;
    const size_t wi = ((size_t)o * 64 + i) * 9 + pq;
    float s = k0 * weight[wi] + k1 * weight[36864 + wi] +
              k2 * weight[73728 + wi] + k3 * weight[110592 + wi];
    float v = co * sp9[b * 9 + pq] * cin[b * 64 + i] * s;
    wfb[((size_t)(b * 9 + pq) * 64 + o) * 64 + i] = (ushort_t)f2bf(v);
  }
}

// ---------------- 4) implicit-GEMM conv from NHWC bf16 ----------------
// block: 512 thr (8 waves), one batch, 4 output rows x 128 cols, all 64 oc.
// wave: 1 row x 128 cols x 32 oc. x tile in LDS [pix=6*132][16ci]; wf in regs.
__global__ __launch_bounds__(512, 4) void conv_bf16(const ushort_t* __restrict__ xb,
                                                    const ushort_t* __restrict__ wfb,
                                                    float* __restrict__ out) {
  const int b  = blockIdx.x >> 5;
  const int h0 = (blockIdx.x & 31) << 2;
  const int tid = threadIdx.x;
  const int lane = tid & 63;
  const int wid = tid >> 6;
  const int rw = wid >> 1;
  const int obase = (wid & 1) << 5;
  const int l31 = lane & 31;
  const int hi = lane >> 5;

  __shared__ __align__(16) short sx[792 * 16];   // 25344 B

  f32x16 acc[4];
#pragma unroll
  for (int nt = 0; nt < 4; ++nt)
#pragma unroll
    for (int r = 0; r < 16; ++r) acc[nt][r] = 0.f;

  const ushort_t* wfb_b = wfb + (size_t)b * 9 * 64 * 64;
  const ushort_t* xb_b  = xb + (size_t)b * 16384 * 64;

  for (int ch = 0; ch < 4; ++ch) {
    const int c0 = ch << 4;
    __syncthreads();
    // stage: 1584 segs of 16 B (pix 0..791 x 2 halves)
    for (int s = tid; s < 1584; s += 512) {
      const int pix = s >> 1, hseg = s & 1;
      const int r = pix / 132;
      const int c = pix - r * 132;
      const int gr = h0 - 1 + r, gc = c - 1;
      uint4 v = make_uint4(0u, 0u, 0u, 0u);
      if ((unsigned)gr < 128u && (unsigned)gc < 128u)
        v = *(const uint4*)(xb_b + (size_t)(gr * 128 + gc) * 64 + c0 + hseg * 8);
      *(uint4*)((char*)sx + s * 16) = v;
    }
    // A-frags from global (L2-hot): 9 taps x 16 B
    bf16x8 af[9];
#pragma unroll
    for (int tap = 0; tap < 9; ++tap)
      af[tap] = *(const bf16x8*)(wfb_b + ((tap * 64 + obase + l31) * 64) + c0 + hi * 8);
    __syncthreads();

#pragma unroll
    for (int p = 0; p < 3; ++p) {
#pragma unroll
      for (int q = 0; q < 3; ++q) {
#pragma unroll
        for (int nt = 0; nt < 4; ++nt) {
          const int pix = (rw + p) * 132 + nt * 32 + q + l31;
          bf16x8 bf = *(const bf16x8*)((const char*)sx + pix * 32 + hi * 16);
          acc[nt] = __builtin_amdgcn_mfma_f32_32x32x16_bf16(af[p * 3 + q], bf, acc[nt], 0, 0, 0);
        }
      }
    }
  }

  const int h = h0 + rw;
#pragma unroll
  for (int nt = 0; nt < 4; ++nt) {
    const int col = nt * 32 + l31;
#pragma unroll
    for (int reg = 0; reg < 16; ++reg) {
      const int o = obase + (reg & 3) + ((reg >> 2) << 3) + (hi << 2);
      out[(((size_t)(b * 64 + o)) * 128 + h) * 128 + col] = acc[nt][reg];
    }
  }
}

// ---------------- old-path conv (fallback when ws is small) ----------------
__global__ __launch_bounds__(512, 2) void conv_fp32(const float* __restrict__ x,
                                                    const ushort_t* __restrict__ wfb,
                                                    float* __restrict__ out) {
  const int b  = blockIdx.x >> 5;
  const int h0 = (blockIdx.x & 31) << 2;
  const int tid = threadIdx.x;
  const int lane = tid & 63;
  const int wid = tid >> 6;
  const int rw = wid >> 1;
  const int obase = (wid & 1) << 5;
  const int l31 = lane & 31;
  const int hi = lane >> 5;

  __shared__ __align__(16) short sx[6 * 132 * 16];
  __shared__ __align__(16) short swf[576 * 16];

  f32x16 acc[4];
#pragma unroll
  for (int nt = 0; nt < 4; ++nt)
#pragma unroll
    for (int r = 0; r < 16; ++r) acc[nt][r] = 0.f;

  for (int ch = 0; ch < 4; ++ch) {
    const int c0 = ch << 4;
    __syncthreads();
    for (int idx = tid; idx < 1584; idx += 512) {
      const int c = idx % 132;
      const int t = idx / 132;
      const int r = t % 6;
      const int h8 = t / 6;
      const int gr = h0 - 1 + r, gc = c - 1;
      uint4 v = make_uint4(0u, 0u, 0u, 0u);
      if ((unsigned)gr < 128u && (unsigned)gc < 128u) {
        const float* xp = x + (((size_t)(b * 64 + c0 + h8 * 8) * 128 + gr) * 128 + gc);
        v.x = f2bf(xp[0])          | (f2bf(xp[16384])     << 16);
        v.y = f2bf(xp[2 * 16384])  | (f2bf(xp[3 * 16384]) << 16);
        v.z = f2bf(xp[4 * 16384])  | (f2bf(xp[5 * 16384]) << 16);
        v.w = f2bf(xp[6 * 16384])  | (f2bf(xp[7 * 16384]) << 16);
      }
      const int pix = r * 132 + c;
      const int byteoff = (pix * 32 + h8 * 16) ^ ((pix & 4) << 2);
      *(uint4*)((char*)sx + byteoff) = v;
    }
    for (int idx = tid; idx < 1152; idx += 512) {
      const int row = idx >> 1, h8 = idx & 1;
      uint4 v = *(const uint4*)(wfb + (((size_t)b * 576 + row) * 64 + c0 + h8 * 8));
      const int byteoff = (row * 32 + h8 * 16) ^ ((row & 4) << 2);
      *(uint4*)((char*)swf + byteoff) = v;
    }
    __syncthreads();

#pragma unroll
    for (int p = 0; p < 3; ++p) {
#pragma unroll
      for (int q = 0; q < 3; ++q) {
        const int arow = (p * 3 + q) * 64 + obase + l31;
        const int abyte = (arow * 32 + hi * 16) ^ ((arow & 4) << 2);
        bf16x8 af = *(const bf16x8*)((const char*)swf + abyte);
#pragma unroll
        for (int nt = 0; nt < 4; ++nt) {
          const int pix = (rw + p) * 132 + nt * 32 + q + l31;
          const int bbyte = (pix * 32 + hi * 16) ^ ((pix & 4) << 2);
          bf16x8 bf = *(const bf16x8*)((const char*)sx + bbyte);
          acc[nt] = __builtin_amdgcn_mfma_f32_32x32x16_bf16(af, bf, acc[nt], 0, 0, 0);
        }
      }
    }
  }

  const int h = h0 + rw;
#pragma unroll
  for (int nt = 0; nt < 4; ++nt) {
    const int col = nt * 32 + l31;
#pragma unroll
    for (int reg = 0; reg < 16; ++reg) {
      const int o = obase + (reg & 3) + ((reg >> 2) << 3) + (hi << 2);
      out[(((size_t)(b * 64 + o)) * 128 + h) * 128 + col] = acc[nt][reg];
    }
  }
}

extern "C" void kernel_launch(void* const* d_in, const int* in_sizes, int n_in,
                              void* d_out, int out_size, void* d_ws, size_t ws_size,
                              hipStream_t stream) {
  const float* x      = (const float*)d_in[0];
  const float* fc_w   = (const float*)d_in[1];
  const float* ch_w   = (const float*)d_in[2];
  const float* ch_b   = (const float*)d_in[3];
  const float* f_w    = (const float*)d_in[4];
  const float* f_b    = (const float*)d_in[5];
  const float* sp_w   = (const float*)d_in[6];
  const float* sp_b   = (const float*)d_in[7];
  const float* k_w    = (const float*)d_in[8];
  const float* k_b    = (const float*)d_in[9];
  const float* fus_w1 = (const float*)d_in[10];
  const float* fus_b1 = (const float*)d_in[11];
  const float* fus_w2 = (const float*)d_in[12];
  const float* fus_b2 = (const float*)d_in[13];
  const float* weight = (const float*)d_in[14];
  float* ws  = (float*)d_ws;
  float* out = (float*)d_out;

  if (ws_size >= NP_NEED) {
    float* part  = ws;
    float* cin   = ws + NP_CIN;
    float* cout_ = ws + NP_COUT;
    float* sp9   = ws + NP_SP9;
    float* k4    = ws + NP_K4;
    ushort_t* wfb = (ushort_t*)((char*)d_ws + NP_WFB_BYTES);
    ushort_t* xb  = (ushort_t*)((char*)d_ws + NP_XB_BYTES);

    convert_kernel<<<1024, 256, 0, stream>>>(x, xb, part);
    att_kernel<<<32, 128, 0, stream>>>(part, 32, fc_w, ch_w, ch_b, f_w, f_b,
                                       sp_w, sp_b, k_w, k_b, fus_w1, fus_b1,
                                       fus_w2, fus_b2, cin, cout_, sp9, k4);
    wf_kernel<<<2048, 256, 0, stream>>>(weight, cin, cout_, sp9, k4, wfb);
    conv_bf16<<<1024, 512, 0, stream>>>(xb, wfb, out);
  } else {
    ushort_t* wfb = (ushort_t*)(ws + WS_WF);
    pool_kernel<<<2048, 256, 0, stream>>>(x, ws + WS_POOLED);
    att_kernel<<<32, 128, 0, stream>>>(ws + WS_POOLED, 0, fc_w, ch_w, ch_b, f_w, f_b,
                                       sp_w, sp_b, k_w, k_b, fus_w1, fus_b1,
                                       fus_w2, fus_b2, ws + WS_CIN, ws + WS_COUT,
                                       ws + WS_SP9, ws + WS_K4);
    wf_kernel<<<2048, 256, 0, stream>>>(weight, ws + WS_CIN, ws + WS_COUT,
                                        ws + WS_SP9, ws + WS_K4, wfb);
    conv_fp32<<<1024, 512, 0, stream>>>(x, wfb, out);
  }
}

// Round 4
// 146.061 us; speedup vs baseline: 1.8993x; 1.8993x over previous
//
#include <hip/hip_runtime.h>
#include <math.h>
#include <stdint.h>

typedef short bf16x8 __attribute__((ext_vector_type(8)));
typedef float f32x16 __attribute__((ext_vector_type(16)));
typedef unsigned short ushort_t;

// ---------------- workspace layout (float offsets) ----------------
#define WS_POOLED 0
#define WS_CIN    2048
#define WS_COUT   4096
#define WS_SP9    6144
#define WS_K4     6432
#define WS_WF     8192   // ushort wfb: 32*9*64*64 = 2.36 MB

static __device__ __forceinline__ unsigned f2bf(float f) {
  unsigned u = __builtin_bit_cast(unsigned, f);
  return (u + 0x7FFFu + ((u >> 16) & 1u)) >> 16;   // RNE
}

// ---------------- 1) global average pool ----------------
__global__ __launch_bounds__(256) void pool_kernel(const float* __restrict__ x,
                                                   float* __restrict__ pooled) {
  const int bc = blockIdx.x;
  const int tid = threadIdx.x;
  const float4* p = (const float4*)(x + (size_t)bc * 16384);
  float s = 0.f;
  for (int j = tid; j < 4096; j += 256) {
    float4 v = p[j];
    s += (v.x + v.y) + (v.z + v.w);
  }
#pragma unroll
  for (int off = 32; off > 0; off >>= 1) s += __shfl_down(s, off, 64);
  __shared__ float red[4];
  if ((tid & 63) == 0) red[tid >> 6] = s;
  __syncthreads();
  if (tid == 0) pooled[bc] = (red[0] + red[1] + red[2] + red[3]) * (1.f / 16384.f);
}

// ---------------- 2) attention chain, one block per batch ----------------
__global__ __launch_bounds__(128) void att_kernel(
    const float* __restrict__ pooled,
    const float* __restrict__ fc_w, const float* __restrict__ ch_w, const float* __restrict__ ch_b,
    const float* __restrict__ f_w,  const float* __restrict__ f_b,
    const float* __restrict__ sp_w, const float* __restrict__ sp_b,
    const float* __restrict__ k_w,  const float* __restrict__ k_b,
    const float* __restrict__ fus_w1, const float* __restrict__ fus_b1,
    const float* __restrict__ fus_w2, const float* __restrict__ fus_b2,
    float* __restrict__ o_cin, float* __restrict__ o_cout,
    float* __restrict__ o_sp9, float* __restrict__ o_k4) {
  const int b = blockIdx.x;
  const int t = threadIdx.x;
  __shared__ float s_pool[64], s_a[16], s_att[128], s_sp[9], s_k[4], s_h[8],
      s_att2[128], s_red[2], s_w12[2];

  if (t < 64) s_pool[t] = pooled[b * 64 + t];
  __syncthreads();

  if (t < 16) {
    float s = 0.f;
    for (int c = 0; c < 64; ++c) s += s_pool[c] * fc_w[t * 64 + c];
    s_a[t] = fmaxf(s, 0.f);
  }
  __syncthreads();

  if (t < 64) {
    float s = ch_b[t];
    for (int j = 0; j < 16; ++j) s += s_a[j] * ch_w[t * 16 + j];
    s_att[t] = 1.f / (1.f + expf(-s));
  } else {
    const int o = t - 64;
    float s = f_b[o];
    for (int j = 0; j < 16; ++j) s += s_a[j] * f_w[o * 16 + j];
    s_att[t] = 1.f / (1.f + expf(-s));
  }
  if (t < 9) {
    float s = sp_b[t];
    for (int j = 0; j < 16; ++j) s += s_a[j] * sp_w[t * 16 + j];
    s_sp[t] = 1.f / (1.f + expf(-s));
  }
  if (t < 4) {
    float s = k_b[t];
    for (int j = 0; j < 16; ++j) s += s_a[j] * k_w[t * 16 + j];
    s_k[t] = s;
  }
  __syncthreads();

  if (t < 8) {
    float s = fus_b1[t];
    for (int c = 0; c < 128; ++c) s += s_att[c] * fus_w1[t * 128 + c];
    s_h[t] = fmaxf(s, 0.f);
  }
  if (t == 127) {
    float m = fmaxf(fmaxf(s_k[0], s_k[1]), fmaxf(s_k[2], s_k[3]));
    float e0 = expf(s_k[0] - m), e1 = expf(s_k[1] - m);
    float e2 = expf(s_k[2] - m), e3 = expf(s_k[3] - m);
    float inv = 1.f / (e0 + e1 + e2 + e3);
    s_k[0] = e0 * inv; s_k[1] = e1 * inv; s_k[2] = e2 * inv; s_k[3] = e3 * inv;
  }
  __syncthreads();

  {
    float s = fus_b2[t];
    for (int j = 0; j < 8; ++j) s += s_h[j] * fus_w2[t * 8 + j];
    s_att2[t] = 1.f / (1.f + expf(-s));
  }
  __syncthreads();

  if (t < 2) {
    float s = 0.f;
    for (int c = 0; c < 64; ++c) s += s_att2[t * 64 + c];
    s_red[t] = s;
  }
  __syncthreads();
  if (t == 0) {
    float m = fmaxf(s_red[0], s_red[1]);
    float e1 = expf(s_red[0] - m), e2 = expf(s_red[1] - m);
    float inv = 1.f / (e1 + e2);
    s_w12[0] = e1 * inv;
    s_w12[1] = e2 * inv;
  }
  __syncthreads();

  if (t < 64) {
    o_cin[b * 64 + t]  = s_w12[0] * s_att[t];
    o_cout[b * 64 + t] = s_w12[1] * s_att[64 + t];
  }
  if (t < 9) o_sp9[b * 9 + t] = s_sp[t];
  if (t < 4) o_k4[b * 4 + t] = s_k[t];
}

// ---------------- 3) fused per-sample weight -> bf16 [b][pq][o][i] ----------------
__global__ __launch_bounds__(256) void wf_kernel(const float* __restrict__ weight,
                                                 const float* __restrict__ cin,
                                                 const float* __restrict__ cout_,
                                                 const float* __restrict__ sp9,
                                                 const float* __restrict__ k4,
                                                 ushort_t* __restrict__ wfb) {
  const int bo = blockIdx.x;              // b*64 + o
  const int b = bo >> 6, o = bo & 63;
  const float co = cout_[b * 64 + o];
  const float k0 = k4[b * 4 + 0], k1 = k4[b * 4 + 1];
  const float k2 = k4[b * 4 + 2], k3 = k4[b * 4 + 3];
  for (int idx = threadIdx.x; idx < 576; idx += 256) {
    const int pq = idx >> 6, i = idx & 63;
    const size_t wi = ((size_t)o * 64 + i) * 9 + pq;
    float s = k0 * weight[wi] + k1 * weight[36864 + wi] +
              k2 * weight[73728 + wi] + k3 * weight[110592 + wi];
    float v = co * sp9[b * 9 + pq] * cin[b * 64 + i] * s;
    wfb[((size_t)(b * 9 + pq) * 64 + o) * 64 + i] = (ushort_t)f2bf(v);
  }
}

// ---------------- 4) single-pass implicit-GEMM conv (fp32 NCHW in) ----------------
// block: 512 thr (8 waves), one batch, 4 output rows x 128 cols, all 64 oc.
// wave: 1 row x 128 cols x 32 oc -> 4 C-frags.
// Staging: thread owns one (ci-oct, row, f4col) slot; 8x float4 loads ->
// bf16 pack -> 4x ds_write_b128, XOR-swizzled. LDS [pix=6*136][16 ci].
__global__ __launch_bounds__(512, 4) void conv_kernel(const float* __restrict__ x,
                                                      const ushort_t* __restrict__ wfb,
                                                      float* __restrict__ out) {
  const int b  = blockIdx.x >> 5;
  const int h0 = (blockIdx.x & 31) << 2;
  const int tid = threadIdx.x;
  const int lane = tid & 63;
  const int wid = tid >> 6;
  const int rw = wid >> 1;              // wave's output row (0..3)
  const int obase = (wid & 1) << 5;     // wave's 32-oc half
  const int l31 = lane & 31;
  const int hi = lane >> 5;

  __shared__ __align__(16) short sx[816 * 16];   // 26112 B

  f32x16 acc[4];
#pragma unroll
  for (int nt = 0; nt < 4; ++nt)
#pragma unroll
    for (int r = 0; r < 16; ++r) acc[nt][r] = 0.f;

  const ushort_t* wfb_b = wfb + (size_t)b * 9 * 64 * 64;

  // staging slot: 408 = 2 octs x 6 rows x 34 f4-cols
  const bool sactive = tid < 408;
  int so = 0, sr = 0, sc = 0;
  if (sactive) { so = tid / 204; const int rem = tid % 204; sr = rem / 34; sc = rem % 34; }
  const int gr  = h0 - 1 + sr;
  const int gcb = sc * 4 - 4;                 // -4 .. 128
  const bool inb = sactive && ((unsigned)gr < 128u) && ((unsigned)gcb < 128u);
  const int pixb = sr * 136 + sc * 4;
  const int key = ((pixb >> 2) & 7) << 4;
  const float* xrow = x + ((size_t)(b * 64) * 16384) + gr * 128 + gcb;

  for (int ch = 0; ch < 4; ++ch) {
    __syncthreads();
    if (inb) {
      const int c0 = ch * 16 + so * 8;
      float4 v[8];
#pragma unroll
      for (int j = 0; j < 8; ++j)
        v[j] = *(const float4*)(xrow + (size_t)(c0 + j) * 16384);
#pragma unroll
      for (int j = 0; j < 4; ++j) {
        uint4 u;
        u.x = f2bf(((const float*)&v[0])[j]) | (f2bf(((const float*)&v[1])[j]) << 16);
        u.y = f2bf(((const float*)&v[2])[j]) | (f2bf(((const float*)&v[3])[j]) << 16);
        u.z = f2bf(((const float*)&v[4])[j]) | (f2bf(((const float*)&v[5])[j]) << 16);
        u.w = f2bf(((const float*)&v[6])[j]) | (f2bf(((const float*)&v[7])[j]) << 16);
        *(uint4*)((char*)sx + ((((pixb + j) * 32) + so * 16) ^ key)) = u;
      }
    } else if (sactive) {
      const uint4 z = make_uint4(0u, 0u, 0u, 0u);
#pragma unroll
      for (int j = 0; j < 4; ++j)
        *(uint4*)((char*)sx + ((((pixb + j) * 32) + so * 16) ^ key)) = z;
    }
    __syncthreads();

#pragma unroll
    for (int p = 0; p < 3; ++p) {
#pragma unroll
      for (int q = 0; q < 3; ++q) {
        const int tap = p * 3 + q;
        bf16x8 af = *(const bf16x8*)(wfb_b + ((tap * 64 + obase + l31) * 64) + ch * 16 + hi * 8);
#pragma unroll
        for (int nt = 0; nt < 4; ++nt) {
          const int pix = (rw + p) * 136 + 3 + q + nt * 32 + l31;
          const int boff = ((pix * 32) + hi * 16) ^ (((pix >> 2) & 7) << 4);
          bf16x8 bf = *(const bf16x8*)((const char*)sx + boff);
          acc[nt] = __builtin_amdgcn_mfma_f32_32x32x16_bf16(af, bf, acc[nt], 0, 0, 0);
        }
      }
    }
  }

  const int h = h0 + rw;
#pragma unroll
  for (int nt = 0; nt < 4; ++nt) {
    const int col = nt * 32 + l31;
#pragma unroll
    for (int reg = 0; reg < 16; ++reg) {
      const int o = obase + (reg & 3) + ((reg >> 2) << 3) + (hi << 2);
      out[(((size_t)(b * 64 + o)) * 128 + h) * 128 + col] = acc[nt][reg];
    }
  }
}

extern "C" void kernel_launch(void* const* d_in, const int* in_sizes, int n_in,
                              void* d_out, int out_size, void* d_ws, size_t ws_size,
                              hipStream_t stream) {
  const float* x      = (const float*)d_in[0];
  const float* fc_w   = (const float*)d_in[1];
  const float* ch_w   = (const float*)d_in[2];
  const float* ch_b   = (const float*)d_in[3];
  const float* f_w    = (const float*)d_in[4];
  const float* f_b    = (const float*)d_in[5];
  const float* sp_w   = (const float*)d_in[6];
  const float* sp_b   = (const float*)d_in[7];
  const float* k_w    = (const float*)d_in[8];
  const float* k_b    = (const float*)d_in[9];
  const float* fus_w1 = (const float*)d_in[10];
  const float* fus_b1 = (const float*)d_in[11];
  const float* fus_w2 = (const float*)d_in[12];
  const float* fus_b2 = (const float*)d_in[13];
  const float* weight = (const float*)d_in[14];
  float* ws  = (float*)d_ws;
  float* out = (float*)d_out;
  ushort_t* wfb = (ushort_t*)(ws + WS_WF);

  pool_kernel<<<2048, 256, 0, stream>>>(x, ws + WS_POOLED);
  att_kernel<<<32, 128, 0, stream>>>(ws + WS_POOLED, fc_w, ch_w, ch_b, f_w, f_b,
                                     sp_w, sp_b, k_w, k_b, fus_w1, fus_b1,
                                     fus_w2, fus_b2, ws + WS_CIN, ws + WS_COUT,
                                     ws + WS_SP9, ws + WS_K4);
  wf_kernel<<<2048, 256, 0, stream>>>(weight, ws + WS_CIN, ws + WS_COUT,
                                      ws + WS_SP9, ws + WS_K4, wfb);
  conv_kernel<<<1024, 512, 0, stream>>>(x, wfb, out);
}